// Round 11
// baseline (115.421 us; speedup 1.0000x reference)
//
#include <hip/hip_runtime.h>
#include <hip/hip_bf16.h>
#include <stdint.h>
#include <stddef.h>

#define AS1 __attribute__((address_space(1)))
#define AS3 __attribute__((address_space(3)))

typedef __attribute__((ext_vector_type(8))) __bf16 bf16x8;
typedef __attribute__((ext_vector_type(4))) float f32x4;
typedef __attribute__((ext_vector_type(4))) unsigned int u32x4;

static __device__ __forceinline__ unsigned short f2bf(float f) {
    unsigned u = __builtin_bit_cast(unsigned, f);
    u += 0x7FFFu + ((u >> 16) & 1u);
    return (unsigned short)(u >> 16);
}

// ---------------- kernel 1: t2 = depthwise (3,1) conv, NHWC bf16 out, H padded by 9 -----
__global__ __launch_bounds__(256) void k_t2prep(const float* __restrict__ x,
                                                const float* __restrict__ w2,
                                                unsigned short* __restrict__ t2p) {
    const int b = blockIdx.x;
    const int cc = (b & 7) * 32;
    const int hp = (b >> 3) % 74;
    const int n  = b / (74 * 8);
    const int t  = threadIdx.x;
    unsigned short* orow = t2p + (size_t)(n * 74 + hp) * (56 * 256);
    const int h = hp - 9;

    if (h < 0 || h >= 56) {
        if (t < 224) {
            int w = t >> 2, c8 = (t & 3) * 8;
            u32x4 z = {0u, 0u, 0u, 0u};
            *(u32x4*)(orow + (size_t)w * 256 + cc + c8) = z;
        }
        return;
    }

    __shared__ float xs[3][32][57];
    for (int idx = t; idx < 1344; idx += 256) {
        int r = idx / 448, rem = idx % 448;
        int ci = rem / 14, q = rem % 14;
        int hy = h - 1 + r;
        f32x4 v = {0.f, 0.f, 0.f, 0.f};
        if (hy >= 0 && hy < 56)
            v = *(const f32x4*)(x + ((size_t)(n * 256 + cc + ci) * 56 + hy) * 56 + q * 4);
        xs[r][ci][q * 4 + 0] = v[0];
        xs[r][ci][q * 4 + 1] = v[1];
        xs[r][ci][q * 4 + 2] = v[2];
        xs[r][ci][q * 4 + 3] = v[3];
    }

    const int c = t & 31;
    const float a0 = w2[(cc + c) * 3 + 0];
    const float a1 = w2[(cc + c) * 3 + 1];
    const float a2 = w2[(cc + c) * 3 + 2];
    __syncthreads();

    #pragma unroll
    for (int i = 0; i < 7; ++i) {
        int w = (t >> 5) + i * 8;
        float v = a0 * xs[0][c][w] + a1 * xs[1][c][w] + a2 * xs[2][c][w];
        orow[(size_t)w * 256 + cc + c] = f2bf(v);
    }
}

// ---------------- kernel 1b: w4 reorder + bf16 convert: w4b[o][k*256+c] = w4[o][c*7+k] ----
__global__ void k_w4conv(const float* __restrict__ w4, unsigned short* __restrict__ w4b) {
    int tid = blockIdx.x * 256 + threadIdx.x;
    int o = tid / 1792, j = tid % 1792;
    int k = j >> 8, c = j & 255;
    w4b[tid] = f2bf(w4[o * 1792 + c * 7 + k]);
}

// ---------------- kernel 2: 256x256 GEMM, m201-style 4-phase/tile with half-tile staging
// Stage granularity = 16KB half-tile (2 gload_lds ops/thread, uniform all waves).
// Iter t: p1 stages B1(t+1)->otherbuf; p3 stages A0(t+2)->curbuf; p4 stages A1(t+2)+
// B0(t+2)->curbuf. Region safety: each region's last READER phase strictly precedes its
// stage phase across a barrier (A halves last read p2 -> staged p3/p4; B-half0 last read
// p3 -> staged p4; B1 goes to the non-current buffer). Clamped end stages re-write
// identical bytes (kt clamped to 27) -> idempotent. vmcnt(6) at p4: outstanding can be
// {B1(t+1), A0/A1/B0(t+2)} = 8 ops -> waits oldest 2 = B1(t+1) => tile t+1 fully landed
// before iter t+1; 3 halves stay in flight (~2-tile prefetch lead).
__global__ __launch_bounds__(512, 2) void k_gemm8(const unsigned short* __restrict__ w4b,
                                                  const unsigned short* __restrict__ t2p,
                                                  float* __restrict__ out) {
    extern __shared__ char lds[];                 // 131072 B: 2 bufs x [A 32K | B 32K]
    const int pix0 = blockIdx.x * 256;
    const int t = threadIdx.x;
    const int l = t & 63, wv = t >> 6;
    const int wr = wv >> 2, wc = wv & 3;

    // ---- staging source bases (bytes), pre-swizzled source (rule 21 involution) ----
    const int srow = t >> 3;                      // 0..63
    const int segp = (t & 7) ^ (srow & 7);
    unsigned abase[4], bbase[4];
    #pragma unroll
    for (int j = 0; j < 4; ++j) {
        int arow = j * 64 + srow;                 // o row
        abase[j] = (unsigned)arow * 3584u + (unsigned)segp * 16u;
        int P = pix0 + j * 64 + srow;             // pixel row (always < 50176)
        int n = P / 3136, r = P % 3136;
        int hh = r / 56, ww = r % 56;
        bbase[j] = (unsigned)(((n * 74 + hh) * 56 + ww) * 512) + (unsigned)segp * 16u;
    }
    const char* w4c = (const char*)w4b;
    const char* t2c = (const char*)t2p;

// A half h of K-tile kt -> buffer bb (j = 2h, 2h+1; 2 ops, uniform)
#define STAGE_AH(kt_, bb_, h_) do {                                                   \
    unsigned _ao = (unsigned)(kt_) * 128u;                                            \
    _Pragma("unroll")                                                                 \
    for (int _j = 2 * (h_); _j < 2 * (h_) + 2; ++_j)                                  \
        __builtin_amdgcn_global_load_lds((const AS1 void*)(w4c + abase[_j] + _ao),    \
            (AS3 void*)(lds + (bb_) + _j * 8192 + wv * 1024), 16, 0, 0);              \
} while (0)
// B half h of K-tile kt -> buffer bb
#define STAGE_BH(kt_, bb_, h_) do {                                                   \
    unsigned _bo = (unsigned)((kt_) >> 2) * 86016u + (unsigned)((kt_) & 3) * 128u;    \
    _Pragma("unroll")                                                                 \
    for (int _j = 2 * (h_); _j < 2 * (h_) + 2; ++_j)                                  \
        __builtin_amdgcn_global_load_lds((const AS1 void*)(t2c + bbase[_j] + _bo),    \
            (AS3 void*)(lds + (bb_) + 32768 + _j * 8192 + wv * 1024), 16, 0, 0);      \
} while (0)

    // ---- fragment-read constants ----
    const int lr = l & 15, lg = l >> 4;
    const int sx = lr & 7;
    const unsigned fo0 = (unsigned)((lg ^ sx) << 4);
    const unsigned fo1 = (unsigned)(((lg + 4) ^ sx) << 4);
    const unsigned aRow = (unsigned)(wc * 8192 + lr * 128);            // + nn*2048
    const unsigned bRow = (unsigned)(32768 + wr * 16384 + lr * 128);   // + m*2048

    f32x4 acc[8][4];
    #pragma unroll
    for (int m = 0; m < 8; ++m)
        #pragma unroll
        for (int nn = 0; nn < 4; ++nn)
            acc[m][nn] = (f32x4){0.f, 0.f, 0.f, 0.f};

    bf16x8 afrag[4][2], bfrag[4][2];

    // ---- prologue: tile0 (4 halves) + tile1 A0,A1,B0 (3 halves); drain tile0 ----
    STAGE_AH(0, 0, 0); STAGE_AH(0, 0, 1); STAGE_BH(0, 0, 0); STAGE_BH(0, 0, 1);
    STAGE_AH(1, 65536, 0); STAGE_AH(1, 65536, 1); STAGE_BH(1, 65536, 0);
    asm volatile("s_waitcnt vmcnt(6)" ::: "memory");   // 14 issued - 8 (tile0) = 6 left
    __builtin_amdgcn_s_barrier();
    asm volatile("" ::: "memory");

    for (int kk = 0; kk < 28; ++kk) {
        const unsigned cur = (unsigned)(kk & 1) * 65536u;
        const unsigned nxt = cur ^ 65536u;
        const int kt1 = (kk < 27) ? kk + 1 : 27;
        const int kt2 = (kk < 26) ? kk + 2 : 27;

        // ========== p1: reads B m0-3 + A n0-1; stage B1(t+1)->nxt; MFMA Q1 ==========
        #pragma unroll
        for (int m = 0; m < 4; ++m) {
            bfrag[m][0] = *(const bf16x8*)(lds + cur + bRow + m * 2048 + fo0);
            bfrag[m][1] = *(const bf16x8*)(lds + cur + bRow + m * 2048 + fo1);
        }
        #pragma unroll
        for (int nn = 0; nn < 2; ++nn) {
            afrag[nn][0] = *(const bf16x8*)(lds + cur + aRow + nn * 2048 + fo0);
            afrag[nn][1] = *(const bf16x8*)(lds + cur + aRow + nn * 2048 + fo1);
        }
        STAGE_BH(kt1, nxt, 1);
        __builtin_amdgcn_s_barrier();
        asm volatile("" ::: "memory");
        __builtin_amdgcn_s_setprio(1);
        #pragma unroll
        for (int m = 0; m < 4; ++m)
            #pragma unroll
            for (int nn = 0; nn < 2; ++nn) {
                acc[m][nn] = __builtin_amdgcn_mfma_f32_16x16x32_bf16(afrag[nn][0], bfrag[m][0], acc[m][nn], 0, 0, 0);
                acc[m][nn] = __builtin_amdgcn_mfma_f32_16x16x32_bf16(afrag[nn][1], bfrag[m][1], acc[m][nn], 0, 0, 0);
            }
        __builtin_amdgcn_s_setprio(0);
        __builtin_amdgcn_s_barrier();
        asm volatile("" ::: "memory");

        // ========== p2: reads A n2-3; MFMA Q2 ==========
        #pragma unroll
        for (int nn = 2; nn < 4; ++nn) {
            afrag[nn][0] = *(const bf16x8*)(lds + cur + aRow + nn * 2048 + fo0);
            afrag[nn][1] = *(const bf16x8*)(lds + cur + aRow + nn * 2048 + fo1);
        }
        __builtin_amdgcn_s_barrier();
        asm volatile("" ::: "memory");
        __builtin_amdgcn_s_setprio(1);
        #pragma unroll
        for (int m = 0; m < 4; ++m)
            #pragma unroll
            for (int nn = 2; nn < 4; ++nn) {
                acc[m][nn] = __builtin_amdgcn_mfma_f32_16x16x32_bf16(afrag[nn][0], bfrag[m][0], acc[m][nn], 0, 0, 0);
                acc[m][nn] = __builtin_amdgcn_mfma_f32_16x16x32_bf16(afrag[nn][1], bfrag[m][1], acc[m][nn], 0, 0, 0);
            }
        __builtin_amdgcn_s_setprio(0);
        __builtin_amdgcn_s_barrier();
        asm volatile("" ::: "memory");

        // ========== p3: reads B m4-7; stage A0(t+2)->cur (A reads done p2); MFMA Q3 ===
        #pragma unroll
        for (int mb = 0; mb < 4; ++mb) {
            bfrag[mb][0] = *(const bf16x8*)(lds + cur + bRow + (4 + mb) * 2048 + fo0);
            bfrag[mb][1] = *(const bf16x8*)(lds + cur + bRow + (4 + mb) * 2048 + fo1);
        }
        STAGE_AH(kt2, cur, 0);
        __builtin_amdgcn_s_barrier();
        asm volatile("" ::: "memory");
        __builtin_amdgcn_s_setprio(1);
        #pragma unroll
        for (int mb = 0; mb < 4; ++mb)
            #pragma unroll
            for (int nn = 2; nn < 4; ++nn) {
                acc[4 + mb][nn] = __builtin_amdgcn_mfma_f32_16x16x32_bf16(afrag[nn][0], bfrag[mb][0], acc[4 + mb][nn], 0, 0, 0);
                acc[4 + mb][nn] = __builtin_amdgcn_mfma_f32_16x16x32_bf16(afrag[nn][1], bfrag[mb][1], acc[4 + mb][nn], 0, 0, 0);
            }
        __builtin_amdgcn_s_setprio(0);
        __builtin_amdgcn_s_barrier();
        asm volatile("" ::: "memory");

        // ========== p4: stage A1(t+2)+B0(t+2)->cur (B0 reads done p3); vmcnt(6); Q4 ===
        STAGE_AH(kt2, cur, 1);
        STAGE_BH(kt2, cur, 0);
        asm volatile("s_waitcnt vmcnt(6)" ::: "memory");   // forces B1(t+1) landed
        __builtin_amdgcn_s_barrier();
        asm volatile("" ::: "memory");
        __builtin_amdgcn_s_setprio(1);
        #pragma unroll
        for (int mb = 0; mb < 4; ++mb)
            #pragma unroll
            for (int nn = 0; nn < 2; ++nn) {
                acc[4 + mb][nn] = __builtin_amdgcn_mfma_f32_16x16x32_bf16(afrag[nn][0], bfrag[mb][0], acc[4 + mb][nn], 0, 0, 0);
                acc[4 + mb][nn] = __builtin_amdgcn_mfma_f32_16x16x32_bf16(afrag[nn][1], bfrag[mb][1], acc[4 + mb][nn], 0, 0, 0);
            }
        __builtin_amdgcn_s_setprio(0);
        __builtin_amdgcn_s_barrier();
        asm volatile("" ::: "memory");
    }
#undef STAGE_AH
#undef STAGE_BH

    // ---- epilogue: C/D layout col(pix)=lane&15, row(o)=(lane>>4)*4+j ----
    #pragma unroll
    for (int m = 0; m < 8; ++m) {
        int P = pix0 + wr * 128 + m * 16 + lr;
        int n = P / 3136, p = P % 3136;
        float* ob = out + (size_t)n * 802816 + p;
        #pragma unroll
        for (int nn = 0; nn < 4; ++nn) {
            int o = wc * 64 + nn * 16 + lg * 4;
            float* op = ob + (size_t)o * 3136;
            op[0 * 3136] = acc[m][nn][0];
            op[1 * 3136] = acc[m][nn][1];
            op[2 * 3136] = acc[m][nn][2];
            op[3 * 3136] = acc[m][nn][3];
        }
    }
}

// ---------------- kernel 3: out *= t1 (depthwise 5x5, LDS-tiled per (n,c) plane) --------
__global__ __launch_bounds__(256) void k_gate(const float* __restrict__ x,
                                              const float* __restrict__ w1,
                                              float* __restrict__ out) {
    const int b = blockIdx.x;
    const int c = b & 255, n = b >> 8;
    const int t = threadIdx.x;
    __shared__ float xs[60][60];

    float* lp = &xs[0][0];
    #pragma unroll
    for (int i = 0; i < 15; ++i) {
        int idx = t + i * 256;
        if (idx < 3600) lp[idx] = 0.f;
    }
    __syncthreads();

    const float* xc = x + (size_t)(n * 256 + c) * 3136;
    #pragma unroll
    for (int k = 0; k < 4; ++k) {
        int j = t + k * 256;
        if (j < 784) {
            f32x4 v = *(const f32x4*)(xc + j * 4);
            int p = j * 4;
            int h = p / 56, w = p % 56;
            xs[h + 2][w + 2 + 0] = v[0];
            xs[h + 2][w + 2 + 1] = v[1];
            xs[h + 2][w + 2 + 2] = v[2];
            xs[h + 2][w + 2 + 3] = v[3];
        }
    }

    const float* wk = w1 + c * 25;
    float wr[25];
    #pragma unroll
    for (int i = 0; i < 25; ++i) wr[i] = wk[i];
    __syncthreads();

    float* oc = out + (size_t)(n * 256 + c) * 3136;
    #pragma unroll
    for (int k = 0; k < 4; ++k) {
        int j = t + k * 256;
        if (j < 784) {
            int p = j * 4;
            int h = p / 56, w = p % 56;
            f32x4 o = *(f32x4*)(oc + p);
            f32x4 t1 = {0.f, 0.f, 0.f, 0.f};
            #pragma unroll
            for (int dy = 0; dy < 5; ++dy)
                #pragma unroll
                for (int dx = 0; dx < 5; ++dx) {
                    float wv = wr[dy * 5 + dx];
                    t1[0] = fmaf(wv, xs[h + dy][w + dx + 0], t1[0]);
                    t1[1] = fmaf(wv, xs[h + dy][w + dx + 1], t1[1]);
                    t1[2] = fmaf(wv, xs[h + dy][w + dx + 2], t1[2]);
                    t1[3] = fmaf(wv, xs[h + dy][w + dx + 3], t1[3]);
                }
            o *= t1;
            *(f32x4*)(oc + p) = o;
        }
    }
}

extern "C" void kernel_launch(void* const* d_in, const int* in_sizes, int n_in,
                              void* d_out, int out_size, void* d_ws, size_t ws_size,
                              hipStream_t stream) {
    const float* x  = (const float*)d_in[0];
    const float* w1 = (const float*)d_in[1];
    const float* w2 = (const float*)d_in[2];
    const float* w4 = (const float*)d_in[3];
    float* out = (float*)d_out;

    const size_t W4B_ELEMS = 256 * 1792;
    const size_t T2P_ELEMS = (size_t)16 * 74 * 56 * 256;
    if (ws_size < (W4B_ELEMS + T2P_ELEMS) * sizeof(unsigned short)) return;
    unsigned short* w4b = (unsigned short*)d_ws;
    unsigned short* t2p = w4b + W4B_ELEMS;

    k_w4conv<<<1792, 256, 0, stream>>>(w4, w4b);
    k_t2prep<<<16 * 74 * 8, 256, 0, stream>>>(x, w2, t2p);
    k_gemm8<<<196, 512, 131072, stream>>>(w4b, t2p, out);
    k_gate<<<4096, 256, 0, stream>>>(x, w1, out);
}